// Round 10
// baseline (1778.416 us; speedup 1.0000x reference)
//
#include <hip/hip_runtime.h>
#include <hip/hip_bf16.h>
#include <hip/hip_cooperative_groups.h>
#include <math.h>

namespace cg = cooperative_groups;

// Problem constants (B=1)
#define SEQ 1024
#define DM 512
#define NH 8
#define HD 64
#define NLAYER 4
#define DIN 128
#define DFF 2048
#define DOUT 390
#define ERROWS 2047  // 2*MAXS-1
#define NSPLIT 4     // flash split-K factor
#define GRID 256     // persistent blocks (1 per CU)

using u16 = unsigned short;
typedef __attribute__((ext_vector_type(8))) short short8;
typedef __attribute__((ext_vector_type(4))) float f32x4;

__device__ inline u16 f2bf(float f){
  __hip_bfloat16 h = __float2bfloat16(f);
  return *(u16*)&h;
}
__device__ inline float bf2f(u16 u){
  __hip_bfloat16 h; *(u16*)&h = u;
  return __bfloat162float(h);
}

// ---------- shared memory union (63488 B < 64 KB) ----------
struct SmemGemm { u16 As[64][72]; u16 Bs[64][72]; };
struct SmemFlash {
  u16 Qs[64][72]; u16 Ks[64][72]; u16 VsT[64][72];
  u16 Es[128][72];
  u16 Ts[64][136];   // Ps tile aliases this storage (barrier-separated)
};
struct SmemPrep { float Ls[64][65]; };
union Smem { SmemGemm g; SmemFlash f; SmemPrep p; };

struct Params {
  const float *x, *emb_W, *emb_b, *Wq, *bq, *Wk, *bk, *Wv, *bv, *Wo, *bo, *Er;
  const float *ln1_g, *ln1_b, *W1, *b1, *W2, *b2, *ln2_g, *ln2_b;
  const float *lnf_g, *lnf_b, *Wi, *bi, *Wf, *bf;
  u16 *xb, *erB, *embT, *wqkvT, *woT, *w1T, *w2T, *wiT, *wfT;
  float *qkvbias;
  u16 *nb, *qkvb, *ob, *mid;
  float *hb, *Op, *mlb, *outp;
};

// ---------- prep stage (grid-stride over 3992 units) ----------
__device__ void prep_stage(Smem& sm, const Params& P, int bid, int tid)
{
  for (int bu = bid; bu < 3992; bu += GRID){
    int b = bu;
    if (b < 128){            // x convert
      int i = (b * 256 + tid) * 4;
      float4 v = *(const float4*)(P.x + i);
      P.xb[i+0]=f2bf(v.x); P.xb[i+1]=f2bf(v.y); P.xb[i+2]=f2bf(v.z); P.xb[i+3]=f2bf(v.w);
      continue;
    }
    b -= 128;
    if (b < 512){            // Er convert
      int i = (b * 256 + tid) * 4;
      if (i < NLAYER * ERROWS * HD){
        float4 v = *(const float4*)(P.Er + i);
        P.erB[i+0]=f2bf(v.x); P.erB[i+1]=f2bf(v.y); P.erB[i+2]=f2bf(v.z); P.erB[i+3]=f2bf(v.w);
      }
      continue;
    }
    b -= 512;
    if (b < 24){             // qkv bias concat
      int i = b * 256 + tid;
      int l = i / 1536, c = i - l * 1536;
      float v = (c < 512) ? P.bq[l * 512 + c]
              : (c < 1024) ? P.bk[l * 512 + c - 512]
                           : P.bv[l * 512 + c - 1024];
      P.qkvbias[i] = v;
      continue;
    }
    b -= 24;

    // weight transpose tiles
    const float* W; u16* WT; int K, N, k0, n0;
    if (b < 16){
      W = P.emb_W; WT = P.embT; K = DIN; N = DM;
      k0 = (b & 1) * 64; n0 = (b >> 1) * 64;
    } else if (b < 1040){
      int i = b - 16, fam = i >> 8, w2 = i & 255, z = w2 >> 6, t2 = w2 & 63;
      K = DM; N = DM; k0 = (t2 & 7) * 64; n0 = (t2 >> 3) * 64;
      const float* Wsrc = (fam == 0) ? P.Wq : (fam == 1) ? P.Wk : (fam == 2) ? P.Wv : P.Wo;
      W = Wsrc + (long)z * DM * DM;
      WT = (fam < 3) ? P.wqkvT + (long)z * 1536 * DM + (long)fam * 512 * DM
                     : P.woT + (long)z * DM * DM;
    } else if (b < 2064){
      int i = b - 1040, z = i >> 8, w2 = i & 255;
      K = DM; N = DFF; k0 = (w2 & 7) * 64; n0 = (w2 >> 3) * 64;
      W = P.W1 + (long)z * DM * DFF; WT = P.w1T + (long)z * DFF * DM;
    } else if (b < 3088){
      int i = b - 2064, z = i >> 8, w2 = i & 255;
      K = DFF; N = DM; k0 = (w2 & 31) * 64; n0 = (w2 >> 5) * 64;
      W = P.W2 + (long)z * DFF * DM; WT = P.w2T + (long)z * DM * DFF;
    } else if (b < 3216){
      int i = b - 3088;
      K = DM; N = 2 * DM; k0 = (i & 7) * 64; n0 = (i >> 3) * 64;
      W = P.Wi; WT = P.wiT;
    } else {
      int i = b - 3216;
      K = 2 * DM; N = DOUT; k0 = (i & 15) * 64; n0 = (i >> 4) * 64;
      W = P.Wf; WT = P.wfT;
    }

    __syncthreads();   // prior iteration's Ls reads complete
    const int cr = (tid & 15) * 4, rr0 = tid >> 4;
#pragma unroll
    for (int rr = 0; rr < 4; rr++){
      int row = rr0 + rr * 16;
      const float* wp = W + (size_t)(k0 + row) * N + n0 + cr;
#pragma unroll
      for (int j = 0; j < 4; j++)
        sm.p.Ls[row][cr + j] = (n0 + cr + j < N) ? wp[j] : 0.f;
    }
    __syncthreads();
    const int nrow = tid >> 2, kc = (tid & 3) * 16;
    const bool valid = (n0 + nrow) < N;
    u16 buf[16];
#pragma unroll
    for (int j = 0; j < 16; j++)
      buf[j] = valid ? f2bf(sm.p.Ls[kc + j][nrow]) : (u16)0;
    u16* out = WT + (size_t)(n0 + nrow) * K + k0 + kc;
    ((uint4*)out)[0] = ((uint4*)buf)[0];
    ((uint4*)out)[1] = ((uint4*)buf)[1];
  }
}

// ---------- GEMM stage, 64x64 tiles, BK=64 ----------
template<bool GELU, bool RES, bool BIAS, bool OUTBF>
__device__ void gemm64(Smem& sm, int tx_, int ty_,
                       const u16* A, const u16* B, const float* bias,
                       const float* res, void* Cout,
                       int N, int K, int lda, int ldb, int ldc, int bid, int tid)
{
  const int w = tid >> 6, lane = tid & 63, m = lane & 15, quad = lane >> 4;
  const int ar = tid >> 2, akc = (tid & 3) * 16;
  const int ntiles = tx_ * ty_;
  for (int t = bid; t < ntiles; t += GRID){
    const int n0 = (t % tx_) * 64, row0 = (t / tx_) * 64;
    f32x4 acc[4];
#pragma unroll
    for (int c = 0; c < 4; c++) acc[c] = (f32x4){0.f, 0.f, 0.f, 0.f};
    for (int k0 = 0; k0 < K; k0 += 64){
      __syncthreads();
      const u16* Ap = &A[(long)(row0 + ar) * lda + k0 + akc];
      const u16* Bp = &B[(long)(n0 + ar) * ldb + k0 + akc];
      *(uint4*)&sm.g.As[ar][akc]     = *(const uint4*)&Ap[0];
      *(uint4*)&sm.g.As[ar][akc + 8] = *(const uint4*)&Ap[8];
      *(uint4*)&sm.g.Bs[ar][akc]     = *(const uint4*)&Bp[0];
      *(uint4*)&sm.g.Bs[ar][akc + 8] = *(const uint4*)&Bp[8];
      __syncthreads();
      short8 a0 = *(const short8*)&sm.g.As[w * 16 + m][quad * 8];
      short8 a1 = *(const short8*)&sm.g.As[w * 16 + m][32 + quad * 8];
#pragma unroll
      for (int c = 0; c < 4; c++){
        short8 b0 = *(const short8*)&sm.g.Bs[c * 16 + m][quad * 8];
        short8 b1 = *(const short8*)&sm.g.Bs[c * 16 + m][32 + quad * 8];
        acc[c] = __builtin_amdgcn_mfma_f32_16x16x32_bf16(a0, b0, acc[c], 0, 0, 0);
        acc[c] = __builtin_amdgcn_mfma_f32_16x16x32_bf16(a1, b1, acc[c], 0, 0, 0);
      }
    }
#pragma unroll
    for (int c = 0; c < 4; c++){
      int col = n0 + c * 16 + m;
      if (col < N){
#pragma unroll
        for (int r = 0; r < 4; r++){
          int row = row0 + w * 16 + quad * 4 + r;
          float val = acc[c][r];
          if (BIAS) val += bias[col];
          if (RES)  val += res[(long)row * ldc + col];
          if (GELU) val = 0.5f * val * (1.f + erff(val * 0.70710678118f));
          if (OUTBF) ((u16*)Cout)[(long)row * ldc + col] = f2bf(val);
          else      ((float*)Cout)[(long)row * ldc + col] = val;
        }
      }
    }
  }
}

// ---------- GEMM stage, 32x64 tiles, BK=64 ----------
template<bool GELU, bool RES, bool BIAS, bool OUTBF>
__device__ void gemm32(Smem& sm, int tx_, int ty_,
                       const u16* A, const u16* B, const float* bias,
                       const float* res, void* Cout,
                       int N, int K, int lda, int ldb, int ldc, int bid, int tid)
{
  const int w = tid >> 6, lane = tid & 63, m = lane & 15, quad = lane >> 4;
  const int rowg = w >> 1, colp = w & 1;
  const int ar = tid >> 3, akc = (tid & 7) * 8;   // A: 32x64
  const int br = tid >> 2, bkc = (tid & 3) * 16;  // B: 64x64
  const int ntiles = tx_ * ty_;
  for (int t = bid; t < ntiles; t += GRID){
    const int n0 = (t % tx_) * 64, row0 = (t / tx_) * 32;
    f32x4 acc[2];
    acc[0] = (f32x4){0.f,0.f,0.f,0.f};
    acc[1] = (f32x4){0.f,0.f,0.f,0.f};
    for (int k0 = 0; k0 < K; k0 += 64){
      __syncthreads();
      *(uint4*)&sm.g.As[ar][akc] = *(const uint4*)&A[(long)(row0 + ar) * lda + k0 + akc];
      const u16* Bp = &B[(long)(n0 + br) * ldb + k0 + bkc];
      *(uint4*)&sm.g.Bs[br][bkc]     = *(const uint4*)&Bp[0];
      *(uint4*)&sm.g.Bs[br][bkc + 8] = *(const uint4*)&Bp[8];
      __syncthreads();
      short8 a0 = *(const short8*)&sm.g.As[rowg * 16 + m][quad * 8];
      short8 a1 = *(const short8*)&sm.g.As[rowg * 16 + m][32 + quad * 8];
#pragma unroll
      for (int c = 0; c < 2; c++){
        int colg = colp * 2 + c;
        short8 b0 = *(const short8*)&sm.g.Bs[colg * 16 + m][quad * 8];
        short8 b1 = *(const short8*)&sm.g.Bs[colg * 16 + m][32 + quad * 8];
        acc[c] = __builtin_amdgcn_mfma_f32_16x16x32_bf16(a0, b0, acc[c], 0, 0, 0);
        acc[c] = __builtin_amdgcn_mfma_f32_16x16x32_bf16(a1, b1, acc[c], 0, 0, 0);
      }
    }
#pragma unroll
    for (int c = 0; c < 2; c++){
      int col = n0 + (colp * 2 + c) * 16 + m;
      if (col < N){
#pragma unroll
        for (int r = 0; r < 4; r++){
          int row = row0 + rowg * 16 + quad * 4 + r;
          float val = acc[c][r];
          if (BIAS) val += bias[col];
          if (RES)  val += res[(long)row * ldc + col];
          if (GELU) val = 0.5f * val * (1.f + erff(val * 0.70710678118f));
          if (OUTBF) ((u16*)Cout)[(long)row * ldc + col] = f2bf(val);
          else      ((float*)Cout)[(long)row * ldc + col] = val;
        }
      }
    }
  }
}

// ---------- LayerNorm stage: wave-per-row, no LDS ----------
__device__ void ln_stage(const float* x, const float* g, const float* b,
                         u16* out, int bid, int tid)
{
  const int w = tid >> 6, lane = tid & 63;
  const int r = bid * 4 + w;
  const float4* xr = (const float4*)(x + (long)r * DM + lane * 8);
  float4 v0 = xr[0], v1 = xr[1];
  float s = v0.x+v0.y+v0.z+v0.w + v1.x+v1.y+v1.z+v1.w;
  float q = v0.x*v0.x+v0.y*v0.y+v0.z*v0.z+v0.w*v0.w
          + v1.x*v1.x+v1.y*v1.y+v1.z*v1.z+v1.w*v1.w;
#pragma unroll
  for (int off = 1; off < 64; off <<= 1){
    s += __shfl_xor(s, off);
    q += __shfl_xor(q, off);
  }
  float mn = s * (1.f / DM);
  float inv = rsqrtf(q * (1.f / DM) - mn * mn + 1e-5f);
  const float4* gp = (const float4*)(g + lane * 8);
  const float4* bp = (const float4*)(b + lane * 8);
  float4 g0 = gp[0], g1 = gp[1], b0 = bp[0], b1 = bp[1];
  u16 tmp[8];
  tmp[0] = f2bf((v0.x - mn) * inv * g0.x + b0.x);
  tmp[1] = f2bf((v0.y - mn) * inv * g0.y + b0.y);
  tmp[2] = f2bf((v0.z - mn) * inv * g0.z + b0.z);
  tmp[3] = f2bf((v0.w - mn) * inv * g0.w + b0.w);
  tmp[4] = f2bf((v1.x - mn) * inv * g1.x + b1.x);
  tmp[5] = f2bf((v1.y - mn) * inv * g1.y + b1.y);
  tmp[6] = f2bf((v1.z - mn) * inv * g1.z + b1.z);
  tmp[7] = f2bf((v1.w - mn) * inv * g1.w + b1.w);
  *(uint4*)(out + (long)r * DM + lane * 8) = *(uint4*)tmp;
}

// ---------- flash stage: 512 units (16 s-tiles x 8 heads x 4 splits) ----------
__device__ void flash_stage(Smem& sm, const u16* qkv, const u16* ErB,
                            float* Op, float* ml, int bid, int tid)
{
  const int w = tid >> 6, lane = tid & 63, m = lane & 15, quad = lane >> 4;
  u16 (*Ps)[72] = reinterpret_cast<u16(*)[72]>(&sm.f.Ts[0][0]);  // alias
  for (int u = bid; u < 512; u += GRID){
    const int s0 = (u & 15) * 64, hh = (u >> 4) & 7, sp = u >> 7;
    __syncthreads();   // prior unit's LDS reads done
    {
      const int r = tid >> 2, kc = (tid & 3) * 16;
      const u16* qp = qkv + (size_t)(s0 + r) * 1536 + hh * HD + kc;
      *(uint4*)&sm.f.Qs[r][kc]     = *(const uint4*)&qp[0];
      *(uint4*)&sm.f.Qs[r][kc + 8] = *(const uint4*)&qp[8];
    }
    __syncthreads();

    const short8 a0 = *(const short8*)&sm.f.Qs[w * 16 + m][quad * 8];
    const short8 a1 = *(const short8*)&sm.f.Qs[w * 16 + m][32 + quad * 8];

    f32x4 accO[4];
#pragma unroll
    for (int c = 0; c < 4; c++) accO[c] = (f32x4){0.f, 0.f, 0.f, 0.f};
    float mrun[4], lrun[4];
#pragma unroll
    for (int r = 0; r < 4; r++){ mrun[r] = -1e30f; lrun[r] = 0.f; }

    const int tbeg = sp * (SEQ / NSPLIT), tend = tbeg + SEQ / NSPLIT;
    for (int t0 = tbeg; t0 < tend; t0 += 64){
      __syncthreads();   // prior PV reads (VsT/Ps) done
      {
        const int r = tid >> 2, kc = (tid & 3) * 16;
        const u16* kp = qkv + (size_t)(t0 + r) * 1536 + 512 + hh * HD + kc;
        *(uint4*)&sm.f.Ks[r][kc]     = *(const uint4*)&kp[0];
        *(uint4*)&sm.f.Ks[r][kc + 8] = *(const uint4*)&kp[8];
        const u16* vp = qkv + (size_t)(t0 + r) * 1536 + 1024 + hh * HD + kc;
        uint4 v0 = *(const uint4*)&vp[0];
        uint4 v1 = *(const uint4*)&vp[8];
        const u16* pv0 = (const u16*)&v0;
        const u16* pv1 = (const u16*)&v1;
#pragma unroll
        for (int j = 0; j < 8; j++) sm.f.VsT[kc + j][r]     = pv0[j];
#pragma unroll
        for (int j = 0; j < 8; j++) sm.f.VsT[kc + 8 + j][r] = pv1[j];
        const int rb = s0 - t0 + 960;
        for (int idx = tid; idx < 127 * 8; idx += 256){
          int er = idx >> 3, ekc = (idx & 7) * 8;
          *(uint4*)&sm.f.Es[er][ekc] = *(const uint4*)&ErB[(size_t)(rb + er) * HD + ekc];
        }
        if (tid < 8){ uint4 z = {0,0,0,0}; *(uint4*)&sm.f.Es[127][tid * 8] = z; }
      }
      __syncthreads();

      f32x4 qk[4], tt[8];
#pragma unroll
      for (int c = 0; c < 4; c++) qk[c] = (f32x4){0.f,0.f,0.f,0.f};
#pragma unroll
      for (int c = 0; c < 8; c++) tt[c] = (f32x4){0.f,0.f,0.f,0.f};
#pragma unroll
      for (int c = 0; c < 4; c++){
        short8 b0 = *(const short8*)&sm.f.Ks[c * 16 + m][quad * 8];
        short8 b1 = *(const short8*)&sm.f.Ks[c * 16 + m][32 + quad * 8];
        qk[c] = __builtin_amdgcn_mfma_f32_16x16x32_bf16(a0, b0, qk[c], 0, 0, 0);
        qk[c] = __builtin_amdgcn_mfma_f32_16x16x32_bf16(a1, b1, qk[c], 0, 0, 0);
      }
#pragma unroll
      for (int c = 0; c < 8; c++){
        short8 b0 = *(const short8*)&sm.f.Es[c * 16 + m][quad * 8];
        short8 b1 = *(const short8*)&sm.f.Es[c * 16 + m][32 + quad * 8];
        tt[c] = __builtin_amdgcn_mfma_f32_16x16x32_bf16(a0, b0, tt[c], 0, 0, 0);
        tt[c] = __builtin_amdgcn_mfma_f32_16x16x32_bf16(a1, b1, tt[c], 0, 0, 0);
      }
#pragma unroll
      for (int c = 0; c < 8; c++)
#pragma unroll
        for (int r = 0; r < 4; r++)
          sm.f.Ts[w * 16 + quad * 4 + r][c * 16 + m] = f2bf(tt[c][r]);
      __syncthreads();

      float sv[4][4];
#pragma unroll
      for (int c = 0; c < 4; c++){
        int j = c * 16 + m;
#pragma unroll
        for (int r = 0; r < 4; r++){
          int i = w * 16 + quad * 4 + r;
          sv[c][r] = qk[c][r] * 0.125f + bf2f(sm.f.Ts[i][i - j + 63]);
        }
      }
      __syncthreads();   // all Ts reads complete before Ps (aliased) writes

      float alpha[4];
#pragma unroll
      for (int r = 0; r < 4; r++){
        float rmax = fmaxf(fmaxf(sv[0][r], sv[1][r]), fmaxf(sv[2][r], sv[3][r]));
#pragma unroll
        for (int off = 1; off < 16; off <<= 1)
          rmax = fmaxf(rmax, __shfl_xor(rmax, off));
        float mnew = fmaxf(mrun[r], rmax);
        alpha[r] = __expf(mrun[r] - mnew);
        mrun[r] = mnew;
        float rsum = 0.f;
#pragma unroll
        for (int c = 0; c < 4; c++){
          float pv = __expf(sv[c][r] - mnew);
          sv[c][r] = pv;
          rsum += pv;
        }
#pragma unroll
        for (int off = 1; off < 16; off <<= 1)
          rsum += __shfl_xor(rsum, off);
        lrun[r] = lrun[r] * alpha[r] + rsum;
      }
#pragma unroll
      for (int c = 0; c < 4; c++)
#pragma unroll
        for (int r = 0; r < 4; r++)
          accO[c][r] *= alpha[r];
#pragma unroll
      for (int c = 0; c < 4; c++)
#pragma unroll
        for (int r = 0; r < 4; r++)
          Ps[w * 16 + quad * 4 + r][c * 16 + m] = f2bf(sv[c][r]);
      __syncthreads();

      short8 pa0 = *(const short8*)&Ps[w * 16 + m][quad * 8];
      short8 pa1 = *(const short8*)&Ps[w * 16 + m][32 + quad * 8];
#pragma unroll
      for (int c = 0; c < 4; c++){
        short8 b0 = *(const short8*)&sm.f.VsT[c * 16 + m][quad * 8];
        short8 b1 = *(const short8*)&sm.f.VsT[c * 16 + m][32 + quad * 8];
        accO[c] = __builtin_amdgcn_mfma_f32_16x16x32_bf16(pa0, b0, accO[c], 0, 0, 0);
        accO[c] = __builtin_amdgcn_mfma_f32_16x16x32_bf16(pa1, b1, accO[c], 0, 0, 0);
      }
    }

    const long base = ((long)sp * NH + hh) * SEQ;
#pragma unroll
    for (int c = 0; c < 4; c++){
#pragma unroll
      for (int r = 0; r < 4; r++){
        int row = s0 + w * 16 + quad * 4 + r;
        Op[(base + row) * HD + c * 16 + m] = accO[c][r];
      }
    }
    if (m == 0){
#pragma unroll
      for (int r = 0; r < 4; r++){
        int row = s0 + w * 16 + quad * 4 + r;
        ml[(base + row) * 2 + 0] = mrun[r];
        ml[(base + row) * 2 + 1] = lrun[r];
      }
    }
  }
}

// ---------- combine split partials: 4 rows per block ----------
__device__ void fcomb_stage(const float* Op, const float* ml, u16* o,
                            int bid, int tid)
{
  const int hh = tid >> 5, c0 = (tid & 31) * 2;
#pragma unroll
  for (int i = 0; i < 4; i++){
    const int s = bid * 4 + i;
    float mm[NSPLIT], ll[NSPLIT];
#pragma unroll
    for (int sp = 0; sp < NSPLIT; sp++){
      long b = (((long)sp * NH + hh) * SEQ + s) * 2;
      mm[sp] = ml[b]; ll[sp] = ml[b + 1];
    }
    float ms = fmaxf(fmaxf(mm[0], mm[1]), fmaxf(mm[2], mm[3]));
    float o0 = 0.f, o1 = 0.f, lsum = 0.f;
#pragma unroll
    for (int sp = 0; sp < NSPLIT; sp++){
      float wsp = __expf(mm[sp] - ms);
      lsum += wsp * ll[sp];
      const float* op = Op + (((long)sp * NH + hh) * SEQ + s) * HD + c0;
      o0 += wsp * op[0];
      o1 += wsp * op[1];
    }
    float inv = 1.f / lsum;
    o[(size_t)s * DM + hh * HD + c0]     = f2bf(o0 * inv);
    o[(size_t)s * DM + hh * HD + c0 + 1] = f2bf(o1 * inv);
  }
}

// ---------- the persistent cooperative mega-kernel ----------
__global__ __launch_bounds__(256)
void net_k(Params P)
{
  __shared__ Smem sm;
  cg::grid_group grid = cg::this_grid();
  const int bid = blockIdx.x, tid = threadIdx.x;

  prep_stage(sm, P, bid, tid);
  grid.sync();

  gemm32<false,false,true,false>(sm, 8, 32, P.xb, P.embT, P.emb_b, nullptr,
                                 P.hb, DM, DIN, DIN, DIN, DM, bid, tid);
  grid.sync();

  for (int l = 0; l < NLAYER; l++){
    const u16* wqkvT_l = P.wqkvT + (size_t)l * 1536 * DM;
    const u16* woT_l   = P.woT + (size_t)l * DM * DM;
    const u16* w1T_l   = P.w1T + (size_t)l * DFF * DM;
    const u16* w2T_l   = P.w2T + (size_t)l * DM * DFF;
    const u16* erB_l   = P.erB + (size_t)l * ERROWS * HD;

    ln_stage(P.hb, P.ln1_g + l * DM, P.ln1_b + l * DM, P.nb, bid, tid);
    grid.sync();
    gemm32<false,false,true,true>(sm, 24, 32, P.nb, wqkvT_l,
                                  P.qkvbias + l * 1536, nullptr,
                                  P.qkvb, 1536, DM, DM, DM, 1536, bid, tid);
    grid.sync();
    flash_stage(sm, P.qkvb, erB_l, P.Op, P.mlb, bid, tid);
    grid.sync();
    fcomb_stage(P.Op, P.mlb, P.ob, bid, tid);
    grid.sync();
    gemm32<false,true,true,false>(sm, 8, 32, P.ob, woT_l, P.bo + l * DM,
                                  P.hb, P.hb, DM, DM, DM, DM, DM, bid, tid);
    grid.sync();
    ln_stage(P.hb, P.ln2_g + l * DM, P.ln2_b + l * DM, P.nb, bid, tid);
    grid.sync();
    gemm64<true,false,true,true>(sm, 32, 16, P.nb, w1T_l, P.b1 + l * DFF,
                                 nullptr, P.mid, DFF, DM, DM, DM, DFF, bid, tid);
    grid.sync();
    gemm32<false,true,true,false>(sm, 8, 32, P.mid, w2T_l, P.b2 + l * DM,
                                  P.hb, P.hb, DM, DFF, DFF, DFF, DM, bid, tid);
    grid.sync();
  }

  ln_stage(P.hb, P.lnf_g, P.lnf_b, P.nb, bid, tid);
  grid.sync();
  gemm64<true,false,true,true>(sm, 16, 16, P.nb, P.wiT, P.bi, nullptr,
                               P.mid, 2 * DM, DM, DM, DM, 2 * DM, bid, tid);
  grid.sync();
  gemm32<false,false,true,false>(sm, 7, 32, P.mid, P.wfT, P.bf, nullptr,
                                 P.outp, DOUT, 2 * DM, 2 * DM, 2 * DM, DOUT, bid, tid);
}

// ---------- fallback: one stage per launch (kernel boundary = sync) ----------
__global__ __launch_bounds__(256)
void stage_k(Params P, int stage, int l)
{
  __shared__ Smem sm;
  const int bid = blockIdx.x, tid = threadIdx.x;
  const u16* wqkvT_l = P.wqkvT + (size_t)l * 1536 * DM;
  const u16* woT_l   = P.woT + (size_t)l * DM * DM;
  const u16* w1T_l   = P.w1T + (size_t)l * DFF * DM;
  const u16* w2T_l   = P.w2T + (size_t)l * DM * DFF;
  const u16* erB_l   = P.erB + (size_t)l * ERROWS * HD;

  switch (stage){
    case 0: prep_stage(sm, P, bid, tid); break;
    case 1: gemm32<false,false,true,false>(sm, 8, 32, P.xb, P.embT, P.emb_b, nullptr,
                                           P.hb, DM, DIN, DIN, DIN, DM, bid, tid); break;
    case 2: ln_stage(P.hb, P.ln1_g + l * DM, P.ln1_b + l * DM, P.nb, bid, tid); break;
    case 3: gemm32<false,false,true,true>(sm, 24, 32, P.nb, wqkvT_l,
                                          P.qkvbias + l * 1536, nullptr,
                                          P.qkvb, 1536, DM, DM, DM, 1536, bid, tid); break;
    case 4: flash_stage(sm, P.qkvb, erB_l, P.Op, P.mlb, bid, tid); break;
    case 5: fcomb_stage(P.Op, P.mlb, P.ob, bid, tid); break;
    case 6: gemm32<false,true,true,false>(sm, 8, 32, P.ob, woT_l, P.bo + l * DM,
                                          P.hb, P.hb, DM, DM, DM, DM, DM, bid, tid); break;
    case 7: ln_stage(P.hb, P.ln2_g + l * DM, P.ln2_b + l * DM, P.nb, bid, tid); break;
    case 8: gemm64<true,false,true,true>(sm, 32, 16, P.nb, w1T_l, P.b1 + l * DFF,
                                         nullptr, P.mid, DFF, DM, DM, DM, DFF, bid, tid); break;
    case 9: gemm32<false,true,true,false>(sm, 8, 32, P.mid, w2T_l, P.b2 + l * DM,
                                          P.hb, P.hb, DM, DFF, DFF, DFF, DM, bid, tid); break;
    case 10: ln_stage(P.hb, P.lnf_g, P.lnf_b, P.nb, bid, tid); break;
    case 11: gemm64<true,false,true,true>(sm, 16, 16, P.nb, P.wiT, P.bi, nullptr,
                                          P.mid, 2 * DM, DM, DM, DM, 2 * DM, bid, tid); break;
    case 12: gemm32<false,false,true,false>(sm, 7, 32, P.mid, P.wfT, P.bf, nullptr,
                                            P.outp, DOUT, 2 * DM, 2 * DM, 2 * DM, DOUT, bid, tid); break;
  }
}

extern "C" void kernel_launch(void* const* d_in, const int* in_sizes, int n_in,
                              void* d_out, int out_size, void* d_ws, size_t ws_size,
                              hipStream_t stream) {
  Params P;
  P.x     = (const float*)d_in[0];
  P.emb_W = (const float*)d_in[1];
  P.emb_b = (const float*)d_in[2];
  P.Wq    = (const float*)d_in[3];
  P.bq    = (const float*)d_in[4];
  P.Wk    = (const float*)d_in[5];
  P.bk    = (const float*)d_in[6];
  P.Wv    = (const float*)d_in[7];
  P.bv    = (const float*)d_in[8];
  P.Wo    = (const float*)d_in[9];
  P.bo    = (const float*)d_in[10];
  P.Er    = (const float*)d_in[11];
  P.ln1_g = (const float*)d_in[12];
  P.ln1_b = (const float*)d_in[13];
  P.W1    = (const float*)d_in[14];
  P.b1    = (const float*)d_in[15];
  P.W2    = (const float*)d_in[16];
  P.b2    = (const float*)d_in[17];
  P.ln2_g = (const float*)d_in[18];
  P.ln2_b = (const float*)d_in[19];
  P.lnf_g = (const float*)d_in[20];
  P.lnf_b = (const float*)d_in[21];
  P.Wi    = (const float*)d_in[22];
  P.bi    = (const float*)d_in[23];
  P.Wf    = (const float*)d_in[24];
  P.bf    = (const float*)d_in[25];

  u16* p = (u16*)d_ws;
  P.xb    = p; p += SEQ * DIN;
  P.embT  = p; p += DM * DIN;
  P.wqkvT = p; p += (size_t)NLAYER * 1536 * DM;
  P.woT   = p; p += (size_t)NLAYER * DM * DM;
  P.w1T   = p; p += (size_t)NLAYER * DFF * DM;
  P.w2T   = p; p += (size_t)NLAYER * DM * DFF;
  P.wiT   = p; p += (size_t)(2 * DM) * DM;
  P.wfT   = p; p += (size_t)448 * (2 * DM);
  P.erB   = p; p += (size_t)NLAYER * ERROWS * HD;
  P.nb    = p; p += SEQ * DM;
  P.qkvb  = p; p += (size_t)SEQ * 1536;
  P.ob    = p; p += SEQ * DM;
  P.mid   = p; p += (size_t)SEQ * DFF;
  P.qkvbias = (float*)p;
  P.hb  = P.qkvbias + NLAYER * 1536;
  P.Op  = P.hb + SEQ * DM;
  P.mlb = P.Op + (size_t)NSPLIT * NH * SEQ * HD;
  P.outp = (float*)d_out;

  void* args[] = { &P };
  hipError_t e = hipLaunchCooperativeKernel((const void*)net_k, dim3(GRID),
                                            dim3(256), args, 0, stream);
  if (e != hipSuccess){
    (void)hipGetLastError();   // clear error state; take the multi-launch path
    dim3 g(GRID), blk(256);
    stage_k<<<g, blk, 0, stream>>>(P, 0, 0);
    stage_k<<<g, blk, 0, stream>>>(P, 1, 0);
    for (int l = 0; l < NLAYER; l++){
      stage_k<<<g, blk, 0, stream>>>(P, 2, l);
      stage_k<<<g, blk, 0, stream>>>(P, 3, l);
      stage_k<<<g, blk, 0, stream>>>(P, 4, l);
      stage_k<<<g, blk, 0, stream>>>(P, 5, l);
      stage_k<<<g, blk, 0, stream>>>(P, 6, l);
      stage_k<<<g, blk, 0, stream>>>(P, 7, l);
      stage_k<<<g, blk, 0, stream>>>(P, 8, l);
      stage_k<<<g, blk, 0, stream>>>(P, 9, l);
    }
    stage_k<<<g, blk, 0, stream>>>(P, 10, 0);
    stage_k<<<g, blk, 0, stream>>>(P, 11, 0);
    stage_k<<<g, blk, 0, stream>>>(P, 12, 0);
  }
}

// Round 11
// 457.538 us; speedup vs baseline: 3.8869x; 3.8869x over previous
//
#include <hip/hip_runtime.h>
#include <hip/hip_bf16.h>
#include <math.h>

// Problem constants (B=1)
#define SEQ 1024
#define DM 512
#define NH 8
#define HD 64
#define NLAYER 4
#define DIN 128
#define DFF 2048
#define DOUT 390
#define ERROWS 2047  // 2*MAXS-1
#define NSPLIT 4     // flash split-K factor

using u16 = unsigned short;
typedef __attribute__((ext_vector_type(8))) short short8;
typedef __attribute__((ext_vector_type(4))) float f32x4;

__device__ inline u16 f2bf(float f){
  __hip_bfloat16 h = __float2bfloat16(f);
  return *(u16*)&h;
}
__device__ inline float bf2f(u16 u){
  __hip_bfloat16 h; *(u16*)&h = u;
  return __bfloat162float(h);
}

__device__ inline float block_sum(float v, float* red){
  int tid = threadIdx.x;
  red[tid] = v; __syncthreads();
  for (int s = 128; s > 0; s >>= 1){
    if (tid < s) red[tid] += red[tid + s];
    __syncthreads();
  }
  float r = red[0]; __syncthreads();
  return r;
}

// ---------- fused one-time prep: converts + transposes, one launch ----------
// grid layout (3992 blocks):
//   [0,128)    : x fp32->bf16
//   [128,640)  : Er fp32->bf16 (guarded)
//   [640,664)  : qkv bias concat
//   [664,3992) : weight transposes (3328 tile-blocks)
__global__ __launch_bounds__(256)
void prep_k(const float* __restrict__ x, const float* __restrict__ Er,
            const float* __restrict__ bq, const float* __restrict__ bk,
            const float* __restrict__ bv,
            const float* __restrict__ emb_W, const float* __restrict__ Wq,
            const float* __restrict__ Wk, const float* __restrict__ Wv,
            const float* __restrict__ Wo, const float* __restrict__ W1,
            const float* __restrict__ W2, const float* __restrict__ Wi,
            const float* __restrict__ Wf,
            u16* __restrict__ xb, u16* __restrict__ erB,
            float* __restrict__ qkvbias,
            u16* __restrict__ embT, u16* __restrict__ wqkvT,
            u16* __restrict__ woT, u16* __restrict__ w1T,
            u16* __restrict__ w2T, u16* __restrict__ wiT,
            u16* __restrict__ wfT)
{
  __shared__ float Ls[64][65];
  int b = blockIdx.x;
  const int tid = threadIdx.x;

  if (b < 128){            // x convert
    int i = (b * 256 + tid) * 4;
    float4 v = *(const float4*)(x + i);
    xb[i+0]=f2bf(v.x); xb[i+1]=f2bf(v.y); xb[i+2]=f2bf(v.z); xb[i+3]=f2bf(v.w);
    return;
  }
  b -= 128;
  if (b < 512){            // Er convert
    int i = (b * 256 + tid) * 4;
    if (i < NLAYER * ERROWS * HD){
      float4 v = *(const float4*)(Er + i);
      erB[i+0]=f2bf(v.x); erB[i+1]=f2bf(v.y); erB[i+2]=f2bf(v.z); erB[i+3]=f2bf(v.w);
    }
    return;
  }
  b -= 512;
  if (b < 24){             // qkv bias concat
    int i = b * 256 + tid;
    int l = i / 1536, c = i - l * 1536;
    float v = (c < 512) ? bq[l * 512 + c]
            : (c < 1024) ? bk[l * 512 + c - 512]
                         : bv[l * 512 + c - 1024];
    qkvbias[i] = v;
    return;
  }
  b -= 24;

  // ---- weight transpose tiles ----
  const float* W; u16* WT; int K, N, k0, n0;
  if (b < 16){
    W = emb_W; WT = embT; K = DIN; N = DM;
    k0 = (b & 1) * 64; n0 = (b >> 1) * 64;
  } else if (b < 1040){
    int i = b - 16, fam = i >> 8, w2 = i & 255, z = w2 >> 6, t2 = w2 & 63;
    K = DM; N = DM; k0 = (t2 & 7) * 64; n0 = (t2 >> 3) * 64;
    const float* Wsrc = (fam == 0) ? Wq : (fam == 1) ? Wk : (fam == 2) ? Wv : Wo;
    W = Wsrc + (long)z * DM * DM;
    WT = (fam < 3) ? wqkvT + (long)z * 1536 * DM + (long)fam * 512 * DM
                   : woT + (long)z * DM * DM;
  } else if (b < 2064){
    int i = b - 1040, z = i >> 8, w2 = i & 255;
    K = DM; N = DFF; k0 = (w2 & 7) * 64; n0 = (w2 >> 3) * 64;
    W = W1 + (long)z * DM * DFF; WT = w1T + (long)z * DFF * DM;
  } else if (b < 3088){
    int i = b - 2064, z = i >> 8, w2 = i & 255;
    K = DFF; N = DM; k0 = (w2 & 31) * 64; n0 = (w2 >> 5) * 64;
    W = W2 + (long)z * DFF * DM; WT = w2T + (long)z * DM * DFF;
  } else if (b < 3216){
    int i = b - 3088;
    K = DM; N = 2 * DM; k0 = (i & 7) * 64; n0 = (i >> 3) * 64;
    W = Wi; WT = wiT;
  } else {
    int i = b - 3216;
    K = 2 * DM; N = DOUT; k0 = (i & 15) * 64; n0 = (i >> 4) * 64;
    W = Wf; WT = wfT;
  }

  const int cr = (tid & 15) * 4, rr0 = tid >> 4;
#pragma unroll
  for (int rr = 0; rr < 4; rr++){
    int row = rr0 + rr * 16;
    const float* wp = W + (size_t)(k0 + row) * N + n0 + cr;
#pragma unroll
    for (int j = 0; j < 4; j++)
      Ls[row][cr + j] = (n0 + cr + j < N) ? wp[j] : 0.f;
  }
  __syncthreads();
  const int nrow = tid >> 2, kc = (tid & 3) * 16;
  const bool valid = (n0 + nrow) < N;
  u16 buf[16];
#pragma unroll
  for (int j = 0; j < 16; j++)
    buf[j] = valid ? f2bf(Ls[kc + j][nrow]) : (u16)0;
  u16* out = WT + (size_t)(n0 + nrow) * K + k0 + kc;
  ((uint4*)out)[0] = ((uint4*)buf)[0];
  ((uint4*)out)[1] = ((uint4*)buf)[1];
}

// ---------- MFMA GEMM, 32x64 tile, BK=64, register-prefetch pipeline ----------
// C[M,N] = A[M,K] @ B + epilogue.  A bf16 [M][K] (lda); B pre-transposed [Npad][K].
// Block = 256 thr (4 waves); wave w: rows (w>>1)*16..+15, col pair (w&1).
// grid.x = N-tiles (64 wide), grid.y = M/32.
template<bool GELU, bool RES, bool BIAS, bool OUTBF>
__global__ __launch_bounds__(256)
void mgemm(const u16* __restrict__ A, const u16* __restrict__ B,
           const float* __restrict__ bias, const float* __restrict__ res,
           void* __restrict__ Cout, int N, int K,
           int lda, int ldb, int ldc)
{
  __shared__ u16 As[32][72];
  __shared__ u16 Bs[64][72];
  const int tid = threadIdx.x;
  const int row0 = blockIdx.y * 32, n0 = blockIdx.x * 64;
  const int w = tid >> 6, lane = tid & 63, m = lane & 15, quad = lane >> 4;
  const int rowg = w >> 1, colp = w & 1;
  const int ar = tid >> 3, akc = (tid & 7) * 8;   // A: 32 rows, 8 thr/row
  const int br = tid >> 2, bkc = (tid & 3) * 16;  // B: 64 rows, 4 thr/row

  f32x4 acc[2];
  acc[0] = (f32x4){0.f,0.f,0.f,0.f};
  acc[1] = (f32x4){0.f,0.f,0.f,0.f};

  // prefetch first K-tile into registers
  uint4 pa  = *(const uint4*)&A[(long)(row0 + ar) * lda + akc];
  uint4 pb0 = *(const uint4*)&B[(long)(n0 + br) * ldb + bkc];
  uint4 pb1 = *(const uint4*)&B[(long)(n0 + br) * ldb + bkc + 8];

  for (int k0 = 0; k0 < K; k0 += 64){
    *(uint4*)&As[ar][akc]     = pa;
    *(uint4*)&Bs[br][bkc]     = pb0;
    *(uint4*)&Bs[br][bkc + 8] = pb1;
    __syncthreads();
    if (k0 + 64 < K){   // issue next tile's loads; they fly during MFMA phase
      pa  = *(const uint4*)&A[(long)(row0 + ar) * lda + k0 + 64 + akc];
      pb0 = *(const uint4*)&B[(long)(n0 + br) * ldb + k0 + 64 + bkc];
      pb1 = *(const uint4*)&B[(long)(n0 + br) * ldb + k0 + 64 + bkc + 8];
    }
    short8 a0 = *(const short8*)&As[rowg * 16 + m][quad * 8];
    short8 a1 = *(const short8*)&As[rowg * 16 + m][32 + quad * 8];
#pragma unroll
    for (int c = 0; c < 2; c++){
      int colg = colp * 2 + c;
      short8 b0 = *(const short8*)&Bs[colg * 16 + m][quad * 8];
      short8 b1 = *(const short8*)&Bs[colg * 16 + m][32 + quad * 8];
      acc[c] = __builtin_amdgcn_mfma_f32_16x16x32_bf16(a0, b0, acc[c], 0, 0, 0);
      acc[c] = __builtin_amdgcn_mfma_f32_16x16x32_bf16(a1, b1, acc[c], 0, 0, 0);
    }
    __syncthreads();
  }

#pragma unroll
  for (int c = 0; c < 2; c++){
    int col = n0 + (colp * 2 + c) * 16 + m;
    if (col < N){
#pragma unroll
      for (int r = 0; r < 4; r++){
        int row = row0 + rowg * 16 + quad * 4 + r;
        float val = acc[c][r];
        if (BIAS) val += bias[col];
        if (RES)  val += res[(long)row * ldc + col];
        if (GELU) val = 0.5f * val * (1.f + erff(val * 0.70710678118f));
        if (OUTBF) ((u16*)Cout)[(long)row * ldc + col] = f2bf(val);
        else      ((float*)Cout)[(long)row * ldc + col] = val;
      }
    }
  }
}

// ---------- LayerNorm: fp32 in, bf16 out ----------
__global__ __launch_bounds__(256)
void ln_k(const float* __restrict__ x, const float* __restrict__ g,
          const float* __restrict__ b, u16* __restrict__ out)
{
  __shared__ float red[256];
  const int r = blockIdx.x, tid = threadIdx.x;
  const float* xr = x + (size_t)r * DM;
  float v0 = xr[tid], v1 = xr[tid + 256];
  float mean = block_sum(v0 + v1, red) * (1.f / DM);
  float d0 = v0 - mean, d1 = v1 - mean;
  float var = block_sum(d0 * d0 + d1 * d1, red) * (1.f / DM);
  float inv = rsqrtf(var + 1e-5f);
  out[(size_t)r * DM + tid]       = f2bf(d0 * inv * g[tid]       + b[tid]);
  out[(size_t)r * DM + tid + 256] = f2bf(d1 * inv * g[tid + 256] + b[tid + 256]);
}

// ---------- split-K flash attention ----------
__global__ __launch_bounds__(256)
void flash_k(const u16* __restrict__ qkv, const u16* __restrict__ ErB,
             float* __restrict__ Op, float* __restrict__ ml)
{
  __shared__ u16 Qs[64][72];
  __shared__ u16 Ks[64][72];
  __shared__ u16 VsT[64][72];
  __shared__ u16 Es[128][72];
  __shared__ u16 Ts[64][136];
  __shared__ u16 Ps[64][72];

  const int tid = threadIdx.x;
  const int s0 = blockIdx.x * 64, hh = blockIdx.y, sp = blockIdx.z;
  const int w = tid >> 6, lane = tid & 63, m = lane & 15, quad = lane >> 4;

  {
    const int r = tid >> 2, kc = (tid & 3) * 16;
    const u16* qp = qkv + (size_t)(s0 + r) * 1536 + hh * HD + kc;
    *(uint4*)&Qs[r][kc]     = *(const uint4*)&qp[0];
    *(uint4*)&Qs[r][kc + 8] = *(const uint4*)&qp[8];
  }
  __syncthreads();

  const short8 a0 = *(const short8*)&Qs[w * 16 + m][quad * 8];
  const short8 a1 = *(const short8*)&Qs[w * 16 + m][32 + quad * 8];

  f32x4 accO[4];
#pragma unroll
  for (int c = 0; c < 4; c++) accO[c] = (f32x4){0.f, 0.f, 0.f, 0.f};
  float mrun[4], lrun[4];
#pragma unroll
  for (int r = 0; r < 4; r++){ mrun[r] = -1e30f; lrun[r] = 0.f; }

  const int tbeg = sp * (SEQ / NSPLIT), tend = tbeg + SEQ / NSPLIT;
  for (int t0 = tbeg; t0 < tend; t0 += 64){
    __syncthreads();
    {
      const int r = tid >> 2, kc = (tid & 3) * 16;
      const u16* kp = qkv + (size_t)(t0 + r) * 1536 + 512 + hh * HD + kc;
      *(uint4*)&Ks[r][kc]     = *(const uint4*)&kp[0];
      *(uint4*)&Ks[r][kc + 8] = *(const uint4*)&kp[8];
      const u16* vp = qkv + (size_t)(t0 + r) * 1536 + 1024 + hh * HD + kc;
      uint4 v0 = *(const uint4*)&vp[0];
      uint4 v1 = *(const uint4*)&vp[8];
      const u16* pv0 = (const u16*)&v0;
      const u16* pv1 = (const u16*)&v1;
#pragma unroll
      for (int j = 0; j < 8; j++) VsT[kc + j][r]     = pv0[j];
#pragma unroll
      for (int j = 0; j < 8; j++) VsT[kc + 8 + j][r] = pv1[j];
      const int rb = s0 - t0 + 960;
      for (int idx = tid; idx < 127 * 8; idx += 256){
        int er = idx >> 3, ekc = (idx & 7) * 8;
        *(uint4*)&Es[er][ekc] = *(const uint4*)&ErB[(size_t)(rb + er) * HD + ekc];
      }
      if (tid < 8){ uint4 z = {0,0,0,0}; *(uint4*)&Es[127][tid * 8] = z; }
    }
    __syncthreads();

    f32x4 qk[4], tt[8];
#pragma unroll
    for (int c = 0; c < 4; c++) qk[c] = (f32x4){0.f,0.f,0.f,0.f};
#pragma unroll
    for (int c = 0; c < 8; c++) tt[c] = (f32x4){0.f,0.f,0.f,0.f};
#pragma unroll
    for (int c = 0; c < 4; c++){
      short8 b0 = *(const short8*)&Ks[c * 16 + m][quad * 8];
      short8 b1 = *(const short8*)&Ks[c * 16 + m][32 + quad * 8];
      qk[c] = __builtin_amdgcn_mfma_f32_16x16x32_bf16(a0, b0, qk[c], 0, 0, 0);
      qk[c] = __builtin_amdgcn_mfma_f32_16x16x32_bf16(a1, b1, qk[c], 0, 0, 0);
    }
#pragma unroll
    for (int c = 0; c < 8; c++){
      short8 b0 = *(const short8*)&Es[c * 16 + m][quad * 8];
      short8 b1 = *(const short8*)&Es[c * 16 + m][32 + quad * 8];
      tt[c] = __builtin_amdgcn_mfma_f32_16x16x32_bf16(a0, b0, tt[c], 0, 0, 0);
      tt[c] = __builtin_amdgcn_mfma_f32_16x16x32_bf16(a1, b1, tt[c], 0, 0, 0);
    }
#pragma unroll
    for (int c = 0; c < 8; c++)
#pragma unroll
      for (int r = 0; r < 4; r++)
        Ts[w * 16 + quad * 4 + r][c * 16 + m] = f2bf(tt[c][r]);
    __syncthreads();

    float sv[4][4];
#pragma unroll
    for (int c = 0; c < 4; c++){
      int j = c * 16 + m;
#pragma unroll
      for (int r = 0; r < 4; r++){
        int i = w * 16 + quad * 4 + r;
        sv[c][r] = qk[c][r] * 0.125f + bf2f(Ts[i][i - j + 63]);
      }
    }
    float alpha[4];
#pragma unroll
    for (int r = 0; r < 4; r++){
      float rmax = fmaxf(fmaxf(sv[0][r], sv[1][r]), fmaxf(sv[2][r], sv[3][r]));
#pragma unroll
      for (int off = 1; off < 16; off <<= 1)
        rmax = fmaxf(rmax, __shfl_xor(rmax, off));
      float mnew = fmaxf(mrun[r], rmax);
      alpha[r] = __expf(mrun[r] - mnew);
      mrun[r] = mnew;
      float rsum = 0.f;
#pragma unroll
      for (int c = 0; c < 4; c++){
        float pv = __expf(sv[c][r] - mnew);
        sv[c][r] = pv;
        rsum += pv;
      }
#pragma unroll
      for (int off = 1; off < 16; off <<= 1)
        rsum += __shfl_xor(rsum, off);
      lrun[r] = lrun[r] * alpha[r] + rsum;
    }
#pragma unroll
    for (int c = 0; c < 4; c++)
#pragma unroll
      for (int r = 0; r < 4; r++)
        accO[c][r] *= alpha[r];
#pragma unroll
    for (int c = 0; c < 4; c++)
#pragma unroll
      for (int r = 0; r < 4; r++)
        Ps[w * 16 + quad * 4 + r][c * 16 + m] = f2bf(sv[c][r]);
    __syncthreads();

    short8 pa0 = *(const short8*)&Ps[w * 16 + m][quad * 8];
    short8 pa1 = *(const short8*)&Ps[w * 16 + m][32 + quad * 8];
#pragma unroll
    for (int c = 0; c < 4; c++){
      short8 b0 = *(const short8*)&VsT[c * 16 + m][quad * 8];
      short8 b1 = *(const short8*)&VsT[c * 16 + m][32 + quad * 8];
      accO[c] = __builtin_amdgcn_mfma_f32_16x16x32_bf16(pa0, b0, accO[c], 0, 0, 0);
      accO[c] = __builtin_amdgcn_mfma_f32_16x16x32_bf16(pa1, b1, accO[c], 0, 0, 0);
    }
  }

  const long base = ((long)sp * NH + hh) * SEQ;
#pragma unroll
  for (int c = 0; c < 4; c++){
#pragma unroll
    for (int r = 0; r < 4; r++){
      int row = s0 + w * 16 + quad * 4 + r;
      Op[(base + row) * HD + c * 16 + m] = accO[c][r];
    }
  }
  if (m == 0){
#pragma unroll
    for (int r = 0; r < 4; r++){
      int row = s0 + w * 16 + quad * 4 + r;
      ml[(base + row) * 2 + 0] = mrun[r];
      ml[(base + row) * 2 + 1] = lrun[r];
    }
  }
}

// combine split partials
__global__ __launch_bounds__(256)
void fcomb_k(const float* __restrict__ Op, const float* __restrict__ ml,
             u16* __restrict__ o)
{
  const int s = blockIdx.x, tid = threadIdx.x;
  const int hh = tid >> 5, c0 = (tid & 31) * 2;
  float mm[NSPLIT], ll[NSPLIT];
#pragma unroll
  for (int sp = 0; sp < NSPLIT; sp++){
    long b = (((long)sp * NH + hh) * SEQ + s) * 2;
    mm[sp] = ml[b]; ll[sp] = ml[b + 1];
  }
  float ms = fmaxf(fmaxf(mm[0], mm[1]), fmaxf(mm[2], mm[3]));
  float o0 = 0.f, o1 = 0.f, lsum = 0.f;
#pragma unroll
  for (int sp = 0; sp < NSPLIT; sp++){
    float wsp = __expf(mm[sp] - ms);
    lsum += wsp * ll[sp];
    const float* op = Op + (((long)sp * NH + hh) * SEQ + s) * HD + c0;
    o0 += wsp * op[0];
    o1 += wsp * op[1];
  }
  float inv = 1.f / lsum;
  o[(size_t)s * DM + hh * HD + c0]     = f2bf(o0 * inv);
  o[(size_t)s * DM + hh * HD + c0 + 1] = f2bf(o1 * inv);
}

extern "C" void kernel_launch(void* const* d_in, const int* in_sizes, int n_in,
                              void* d_out, int out_size, void* d_ws, size_t ws_size,
                              hipStream_t stream) {
  const float* x     = (const float*)d_in[0];
  const float* emb_W = (const float*)d_in[1];
  const float* emb_b = (const float*)d_in[2];
  const float* Wq    = (const float*)d_in[3];
  const float* bq    = (const float*)d_in[4];
  const float* Wk    = (const float*)d_in[5];
  const float* bk    = (const float*)d_in[6];
  const float* Wv    = (const float*)d_in[7];
  const float* bv    = (const float*)d_in[8];
  const float* Wo    = (const float*)d_in[9];
  const float* bo    = (const float*)d_in[10];
  const float* Er    = (const float*)d_in[11];
  const float* ln1_g = (const float*)d_in[12];
  const float* ln1_b = (const float*)d_in[13];
  const float* W1    = (const float*)d_in[14];
  const float* b1    = (const float*)d_in[15];
  const float* W2    = (const float*)d_in[16];
  const float* b2    = (const float*)d_in[17];
  const float* ln2_g = (const float*)d_in[18];
  const float* ln2_b = (const float*)d_in[19];
  const float* lnf_g = (const float*)d_in[20];
  const float* lnf_b = (const float*)d_in[21];
  const float* Wi    = (const float*)d_in[22];
  const float* bi    = (const float*)d_in[23];
  const float* Wf    = (const float*)d_in[24];
  const float* bfin  = (const float*)d_in[25];

  // ---- workspace carve ----
  u16* p = (u16*)d_ws;
  u16* xb    = p; p += SEQ * DIN;
  u16* embT  = p; p += DM * DIN;
  u16* wqkvT = p; p += (size_t)NLAYER * 1536 * DM;
  u16* woT   = p; p += (size_t)NLAYER * DM * DM;
  u16* w1T   = p; p += (size_t)NLAYER * DFF * DM;
  u16* w2T   = p; p += (size_t)NLAYER * DM * DFF;
  u16* wiT   = p; p += (size_t)(2 * DM) * DM;
  u16* wfT   = p; p += (size_t)448 * (2 * DM);
  u16* erB   = p; p += (size_t)NLAYER * ERROWS * HD;
  u16* nb    = p; p += SEQ * DM;
  u16* qkvb  = p; p += (size_t)SEQ * 1536;
  u16* ob    = p; p += SEQ * DM;
  u16* mid   = p; p += (size_t)SEQ * DFF;
  float* qkvbias = (float*)p;
  float* hb  = qkvbias + NLAYER * 1536;
  float* Op  = hb + SEQ * DM;
  float* mlb = Op + (size_t)NSPLIT * NH * SEQ * HD;

  dim3 blk(256);

  // ---- single prep launch ----
  prep_k<<<3992, blk, 0, stream>>>(
      x, Er, bq, bk, bv, emb_W, Wq, Wk, Wv, Wo, W1, W2, Wi, Wf,
      xb, erB, qkvbias, embT, wqkvT, woT, w1T, w2T, wiT, wfT);

  // grids: x = N/64, y = M/32 = 32
  dim3 g512(8, 32), gqkv(24, 32), gff(32, 32), gwi(16, 32), gout(7, 32);
  dim3 gfl(16, NH, NSPLIT);

  // ---- embedding ----
  mgemm<false, false, true, false><<<g512, blk, 0, stream>>>(
      xb, embT, emb_b, nullptr, hb, DM, DIN, DIN, DIN, DM);

  for (int l = 0; l < NLAYER; l++) {
    const u16* wqkvT_l = wqkvT + (size_t)l * 1536 * DM;
    const u16* woT_l   = woT + (size_t)l * DM * DM;
    const u16* w1T_l   = w1T + (size_t)l * DFF * DM;
    const u16* w2T_l   = w2T + (size_t)l * DM * DFF;
    const u16* erB_l   = erB + (size_t)l * ERROWS * HD;

    ln_k<<<SEQ, blk, 0, stream>>>(hb, ln1_g + l * DM, ln1_b + l * DM, nb);
    mgemm<false, false, true, true><<<gqkv, blk, 0, stream>>>(
        nb, wqkvT_l, qkvbias + l * 1536, nullptr, qkvb, 1536, DM, DM, DM, 1536);

    flash_k<<<gfl, blk, 0, stream>>>(qkvb, erB_l, Op, mlb);
    fcomb_k<<<SEQ, blk, 0, stream>>>(Op, mlb, ob);

    mgemm<false, true, true, false><<<g512, blk, 0, stream>>>(
        ob, woT_l, bo + l * DM, hb, hb, DM, DM, DM, DM, DM);

    ln_k<<<SEQ, blk, 0, stream>>>(hb, ln2_g + l * DM, ln2_b + l * DM, nb);
    mgemm<true, false, true, true><<<gff, blk, 0, stream>>>(
        nb, w1T_l, b1 + l * DFF, nullptr, mid, DFF, DM, DM, DM, DFF);
    mgemm<false, true, true, false><<<g512, blk, 0, stream>>>(
        mid, w2T_l, b2 + l * DM, hb, hb, DM, DFF, DFF, DFF, DM);
  }

  ln_k<<<SEQ, blk, 0, stream>>>(hb, lnf_g, lnf_b, nb);
  mgemm<true, false, true, true><<<gwi, blk, 0, stream>>>(
      nb, wiT, bi, nullptr, mid, 2 * DM, DM, DM, DM, 2 * DM);
  mgemm<false, false, true, false><<<gout, blk, 0, stream>>>(
      mid, wfT, bfin, nullptr, (float*)d_out, DOUT, 2 * DM, 2 * DM, 2 * DM, DOUT);
}